// Round 19
// baseline (95.748 us; speedup 1.0000x reference)
//
#include <hip/hip_runtime.h>

#define DEV __device__ __forceinline__

typedef __attribute__((ext_vector_type(4))) float f32x4;
typedef __attribute__((ext_vector_type(16))) float f32x16;
typedef __attribute__((ext_vector_type(8))) short s16x8;

static constexpr int TB  = 2;
static constexpr int TT  = 2048;
static constexpr int TD  = 1024;
static constexpr int TH  = 16;
static constexpr int THD = 64;
static constexpr int TN3 = 3072;
static constexpr int TM  = TB * TT;   // 4096

// ---- workspace layout (bytes) ----
#define WS_XB     1024u                       // bf16 [4096][1024]      8 MiB
#define WS_WQKVT  (WS_XB + 8388608u)          // bf16 [3072][1024]      6 MiB
#define WS_WOUTT  (WS_WQKVT + 6291456u)       // bf16 [1024][1024]      2 MiB
#define WS_QKV    (WS_WOUTT + 2097152u)       // bf16 [4096][3072]     24 MiB
#define WS_VT     (WS_QKV + 25165824u)        // bf16 [32][64][2048]    8 MiB
#define WS_CTX    (WS_VT + 8388608u)          // bf16 [4096][1024]      8 MiB

DEV unsigned short f2bf(float f) {
  unsigned int u = __builtin_bit_cast(unsigned int, f);
  u += 0x7FFFu + ((u >> 16) & 1u);
  return (unsigned short)(u >> 16);
}
DEV f32x4 mfma16(s16x8 a, s16x8 b, f32x4 c) {
  return __builtin_amdgcn_mfma_f32_16x16x32_bf16(a, b, c, 0, 0, 0);
}
DEV f32x16 mfma32(s16x8 a, s16x8 b, f32x16 c) {
  return __builtin_amdgcn_mfma_f32_32x32x16_bf16(a, b, c, 0, 0, 0);
}
DEV void gload_lds16(const void* g, void* l) {
  __builtin_amdgcn_global_load_lds(
      (const __attribute__((address_space(1))) void*)g,
      (__attribute__((address_space(3))) void*)l, 16, 0, 0);
}
DEV unsigned int cvtpk(float lo, float hi_) {
  unsigned int r;
  asm("v_cvt_pk_bf16_f32 %0, %1, %2" : "=v"(r) : "v"(lo), "v"(hi_));
  return r;
}
DEV void plswap(unsigned int& a, unsigned int& b) {
  asm("v_permlane32_swap_b32 %0, %1" : "+v"(a), "+v"(b));
}

// ---- inline dtype probe: wave-uniform. fp32 viewed as u16 -> ~47% of even
// samples have exp>=135; bf16 N(0,1) -> exactly 0.
DEV bool is_bf16(const void* x) {
  uint4 v = ((const uint4*)x)[threadIdx.x & 63];
  unsigned int w[4] = {v.x, v.y, v.z, v.w};
  int hit = 0;
#pragma unroll
  for (int k = 0; k < 4; ++k) {
    if (((w[k] >> 7) & 0xFF) >= 135) hit++;
    if (((w[k] >> 23) & 0xFF) >= 135) hit++;
  }
  return __ballot(hit > 0) == 0ULL;
}

// ---- kernel 1: fused prep: W transposes (blocks 0..1023) + x cast (1024..3071;
// cast skipped when input already bf16 since GEMM1 then reads x directly)
__global__ __launch_bounds__(256) void prep_kernel(const void* __restrict__ x,
                                                   const void* __restrict__ wqkv,
                                                   const void* __restrict__ wout,
                                                   unsigned short* __restrict__ xb,
                                                   unsigned short* __restrict__ wqkvt,
                                                   unsigned short* __restrict__ woutt) {
  __shared__ unsigned short tile[64 * 65];
  const int bid = blockIdx.x;
  const bool bf = is_bf16(x);
  if (bid < 1024) {
    const void* W; unsigned short* Wt; int N, k0, n0;
    if (bid < 768) { W = wqkv; Wt = wqkvt; N = TN3; k0 = (bid & 15) * 64; n0 = (bid >> 4) * 64; }
    else { int id = bid - 768; W = wout; Wt = woutt; N = TD; k0 = (id & 15) * 64; n0 = (id >> 4) * 64; }
    for (int e = threadIdx.x; e < 4096; e += 256) {
      int kr = e >> 6, nc = e & 63;
      unsigned short v;
      if (bf) v = ((const unsigned short*)W)[(size_t)(k0 + kr) * N + n0 + nc];
      else    v = f2bf(((const float*)W)[(size_t)(k0 + kr) * N + n0 + nc]);
      tile[kr * 65 + nc] = v;
    }
    __syncthreads();
    for (int e = threadIdx.x; e < 4096; e += 256) {
      int nr = e >> 6, kc = e & 63;
      Wt[(size_t)(n0 + nr) * TD + k0 + kc] = tile[kc * 65 + nr];
    }
  } else {
    if (bf) return;   // GEMM1 reads x directly in bf16 mode
    int i = (bid - 1024) * 256 + threadIdx.x;
    if (i >= (TM * TD) / 8) return;
    const float* s = (const float*)x + (size_t)i * 8;
    unsigned int w0 = (unsigned int)f2bf(s[0]) | ((unsigned int)f2bf(s[1]) << 16);
    unsigned int w1 = (unsigned int)f2bf(s[2]) | ((unsigned int)f2bf(s[3]) << 16);
    unsigned int w2 = (unsigned int)f2bf(s[4]) | ((unsigned int)f2bf(s[5]) << 16);
    unsigned int w3 = (unsigned int)f2bf(s[6]) | ((unsigned int)f2bf(s[7]) << 16);
    uint4 o; o.x = w0; o.y = w1; o.z = w2; o.w = w3;
    ((uint4*)xb)[i] = o;
  }
}

// ---- kernel 2: 256x192-tile GEMM1, 4-phase fine-grained schedule.
// 256 blocks = full CU fill, BK=64, 8 waves (2M x 4N, per-wave 128x48).
// Phases (12 MFMA each): P1 m0-3*k0 (reads 7) | P2 m4-7*k0 (4) |
// P3 m0-3*k1 (7) | P4 m4-7*k1 (4). Staging of t+1 spread 3/2/2/0 in
// consumption order [A0,A2,B0 | B1,B2 | A1,A3]. Waits: vmcnt(3)@P1-end
// (covers A1,A3, >=3 phases old), vmcnt(2)@P4-end (covers next-P1's 5
// rounds, >=2 phases old). Ledger verified prologue/steady/tail.
__global__ __launch_bounds__(512, 2) void gemm1_kernel(const unsigned short* __restrict__ Axb,
                                                       const unsigned short* __restrict__ xraw,
                                                       const unsigned short* __restrict__ Bt,
                                                       unsigned short* __restrict__ C,
                                                       unsigned short* __restrict__ vtb,
                                                       int Mn, int Nn, int Kn) {
  __shared__ unsigned short lA[2][256 * 64];   // 32KB each
  __shared__ unsigned short lB[2][192 * 64];   // 24KB each
  const int tid = threadIdx.x;
  const int lane = tid & 63;
  const int wid = tid >> 6;                 // 0..7
  const int wm = wid >> 2, wn = wid & 3;    // 2M x 4N
  const int l15 = lane & 15, lg = lane >> 4;

  const int nby = Nn / 192;                 // 16
  const int nwg = (Mn >> 8) * nby;          // 256
  const int cpx = nwg >> 3;
  const int bid = blockIdx.x;
  const int swz = (bid & 7) * cpx + (bid >> 3);
  const int bm = swz / nby, bn = swz % nby;
  const int row0 = bm << 8, col0 = bn * 192;

  const bool bf = is_bf16(xraw);
  const unsigned short* Abase = bf ? xraw : Axb;

  const int srow = tid >> 3;                // 0..63
  const int scol = ((tid & 7) ^ (srow & 7)) * 8;
  const unsigned short* aS = Abase + (size_t)(row0 + srow) * Kn + scol;
  const unsigned short* bS = Bt + (size_t)(col0 + srow) * Kn + scol;
  const size_t r64 = (size_t)64 * Kn;

  // staging split in consumption order: [A0,A2,B0] [B1,B2] [A1,A3]
#define STG_P1(da, db, koff) do {                           \
    gload_lds16(aS + (koff),           (da) + tid * 8);     \
    gload_lds16(aS + (koff) + 2 * r64, (da) + tid * 8 + 8192); \
    gload_lds16(bS + (koff),           (db) + tid * 8);     \
  } while (0)
#define STG_P2(db, koff) do {                               \
    gload_lds16(bS + (koff) + r64,     (db) + tid * 8 + 4096); \
    gload_lds16(bS + (koff) + 2 * r64, (db) + tid * 8 + 8192); \
  } while (0)
#define STG_P3(da, koff) do {                               \
    gload_lds16(aS + (koff) + r64,     (da) + tid * 8 + 4096); \
    gload_lds16(aS + (koff) + 3 * r64, (da) + tid * 8 + 12288); \
  } while (0)

  f32x4 acc[8][3];
#pragma unroll
  for (int m = 0; m < 8; ++m)
#pragma unroll
    for (int n = 0; n < 3; ++n) acc[m][n] = (f32x4){0.f, 0.f, 0.f, 0.f};

  const int sa = l15 & 7;
  const int kc0 = (lg ^ sa) * 8;
  const int kc1 = ((4 + lg) ^ sa) * 8;
  const int aRow = (wm * 128 + l15) * 64;
  const int bRow = (wn * 48 + l15) * 64;

  // prologue: stage tile 0 in consumption order, complete first 5 rounds
  STG_P1(&lA[0][0], &lB[0][0], 0);
  STG_P2(&lB[0][0], 0);
  STG_P3(&lA[0][0], 0);
  asm volatile("s_waitcnt vmcnt(2)" ::: "memory");
  __builtin_amdgcn_s_barrier();

  const int nt = Kn >> 6;
  for (int t = 0; t < nt; ++t) {
    const unsigned short* la = &lA[t & 1][0];
    const unsigned short* lb = &lB[t & 1][0];
    unsigned short* na = &lA[(t + 1) & 1][0];
    unsigned short* nb = &lB[(t + 1) & 1][0];
    const int koff = (t + 1) << 6;
    const bool more = (t + 1 < nt);

    s16x8 av[4], bv[3];

    // ---- P1: read A m0-3 k0 + B k0 | stage A0,A2,B0(t+1) | 12 MFMA | vmcnt
#pragma unroll
    for (int m = 0; m < 4; ++m) av[m] = *(const s16x8*)&la[aRow + m * 1024 + kc0];
#pragma unroll
    for (int n = 0; n < 3; ++n) bv[n] = *(const s16x8*)&lb[bRow + n * 1024 + kc0];
    if (more) STG_P1(na, nb, koff);
    __builtin_amdgcn_s_barrier();
    asm volatile("s_waitcnt lgkmcnt(0)" ::: "memory");
    __builtin_amdgcn_sched_barrier(0);
    __builtin_amdgcn_s_setprio(1);
#pragma unroll
    for (int m = 0; m < 4; ++m)
#pragma unroll
      for (int n = 0; n < 3; ++n)
        acc[m][n] = mfma16(av[m], bv[n], acc[m][n]);
    __builtin_amdgcn_s_setprio(0);
    if (more) asm volatile("s_waitcnt vmcnt(3)" ::: "memory");   // A1,A3(t) done
    else      asm volatile("s_waitcnt vmcnt(0)" ::: "memory");
    __builtin_amdgcn_s_barrier();

    // ---- P2: read A m4-7 k0 | stage B1,B2(t+1) | 12 MFMA
#pragma unroll
    for (int m = 0; m < 4; ++m) av[m] = *(const s16x8*)&la[aRow + (4 + m) * 1024 + kc0];
    if (more) STG_P2(nb, koff);
    __builtin_amdgcn_s_barrier();
    asm volatile("s_waitcnt lgkmcnt(0)" ::: "memory");
    __builtin_amdgcn_sched_barrier(0);
    __builtin_amdgcn_s_setprio(1);
#pragma unroll
    for (int m = 0; m < 4; ++m)
#pragma unroll
      for (int n = 0; n < 3; ++n)
        acc[4 + m][n] = mfma16(av[m], bv[n], acc[4 + m][n]);
    __builtin_amdgcn_s_setprio(0);
    __builtin_amdgcn_s_barrier();

    // ---- P3: read A m0-3 k1 + B k1 | stage A1,A3(t+1) | 12 MFMA
#pragma unroll
    for (int m = 0; m < 4; ++m) av[m] = *(const s16x8*)&la[aRow + m * 1024 + kc1];
#pragma unroll
    for (int n = 0; n < 3; ++n) bv[n] = *(const s16x8*)&lb[bRow + n * 1024 + kc1];
    if (more) STG_P3(na, koff);
    __builtin_amdgcn_s_barrier();
    asm volatile("s_waitcnt lgkmcnt(0)" ::: "memory");
    __builtin_amdgcn_sched_barrier(0);
    __builtin_amdgcn_s_setprio(1);
#pragma unroll
    for (int m = 0; m < 4; ++m)
#pragma unroll
      for (int n = 0; n < 3; ++n)
        acc[m][n] = mfma16(av[m], bv[n], acc[m][n]);
    __builtin_amdgcn_s_setprio(0);
    __builtin_amdgcn_s_barrier();

    // ---- P4: read A m4-7 k1 | 12 MFMA | vmcnt(2) | barrier
#pragma unroll
    for (int m = 0; m < 4; ++m) av[m] = *(const s16x8*)&la[aRow + (4 + m) * 1024 + kc1];
    __builtin_amdgcn_s_barrier();
    asm volatile("s_waitcnt lgkmcnt(0)" ::: "memory");
    __builtin_amdgcn_sched_barrier(0);
    __builtin_amdgcn_s_setprio(1);
#pragma unroll
    for (int m = 0; m < 4; ++m)
#pragma unroll
      for (int n = 0; n < 3; ++n)
        acc[4 + m][n] = mfma16(av[m], bv[n], acc[4 + m][n]);
    __builtin_amdgcn_s_setprio(0);
    if (more) asm volatile("s_waitcnt vmcnt(2)" ::: "memory");   // next-P1 rounds done
    else      asm volatile("s_waitcnt vmcnt(0)" ::: "memory");
    __builtin_amdgcn_s_barrier();
  }
#undef STG_P1
#undef STG_P2
#undef STG_P3

  // epilogue: per-fragment branch at column 2048 (fragments never straddle)
  unsigned short* cw = C + (size_t)(row0 + wm * 128 + lg * 4) * Nn + col0 + wn * 48 + l15;
#pragma unroll
  for (int m = 0; m < 8; ++m)
#pragma unroll
    for (int n = 0; n < 3; ++n) {
      const int cbase = col0 + wn * 48 + n * 16;
      if (cbase < 2048) {
#pragma unroll
        for (int j = 0; j < 4; ++j)
          cw[(size_t)(m * 16 + j) * Nn + n * 16] = f2bf(acc[m][n][j]);
      } else {
        int tg = row0 + wm * 128 + lg * 4 + m * 16;
        int bb = tg >> 11, tt = tg & 2047;
        int cc2 = cbase + l15 - 2048;
        int h = cc2 >> 6, d = cc2 & 63;
        unsigned short* dst = vtb + (((size_t)(bb * 16 + h) * 64 + d) << 11) + tt;
        uint2 pk;
        pk.x = cvtpk(acc[m][n][0], acc[m][n][1]);
        pk.y = cvtpk(acc[m][n][2], acc[m][n][3]);
        *(uint2*)dst = pk;
      }
    }
}

// ---- kernel 3: GEMM2 (round-13..18 validated version)
__global__ __launch_bounds__(256, 2) void gemm_bt2_kernel(const unsigned short* __restrict__ A,
                                                          const unsigned short* __restrict__ Bt,
                                                          void* __restrict__ Cout,
                                                          int Mn, int Nn, int Kn,
                                                          const unsigned short* __restrict__ xprobe) {
  __shared__ unsigned short lA[3][128 * 64];   // 16KB each
  __shared__ unsigned short lB[3][64 * 64];    // 8KB each
  const int tid  = threadIdx.x;
  const int lane = tid & 63, wid = tid >> 6;
  const int wr = wid >> 1, wc = wid & 1;       // 2M x 2N waves
  const int l15 = lane & 15, lg = lane >> 4;
  const int row0 = blockIdx.x * 128, col0 = blockIdx.y * 64;

  const bool obf = is_bf16(xprobe);

  f32x4 acc[4][2];
#pragma unroll
  for (int m = 0; m < 4; ++m)
#pragma unroll
    for (int n = 0; n < 2; ++n) acc[m][n] = (f32x4){0.f, 0.f, 0.f, 0.f};

  const int srow = tid >> 3;
  const int scol = ((tid & 7) ^ (srow & 7)) * 8;
  const unsigned short* aS = A  + (size_t)(row0 + srow) * Kn + scol;
  const unsigned short* bS = Bt + (size_t)(col0 + srow) * Kn + scol;
  const size_t r32 = (size_t)32 * Kn;

#define STG2(bi, koff) do {                                                 \
    unsigned short* _da = &lA[bi][0] + tid * 8;                             \
    unsigned short* _db = &lB[bi][0] + tid * 8;                             \
    gload_lds16(aS + (koff),            _da);                               \
    gload_lds16(aS + (koff) + r32,      _da + 2048);                        \
    gload_lds16(aS + (koff) + 2 * r32,  _da + 4096);                        \
    gload_lds16(aS + (koff) + 3 * r32,  _da + 6144);                        \
    gload_lds16(bS + (koff),            _db);                               \
    gload_lds16(bS + (koff) + r32,      _db + 2048);                        \
  } while (0)

  const int sa = l15 & 7;
  const int kc0 = (lg ^ sa) * 8;
  const int kc1 = ((4 + lg) ^ sa) * 8;
  const int aoff = (wr * 64 + l15) * 64;   // + m*1024
  const int boff = (wc * 32 + l15) * 64;   // + n*1024

  const int nt = Kn >> 6;
  STG2(0, 0);
  STG2(1, 64);
  asm volatile("s_waitcnt vmcnt(6)" ::: "memory");
  __builtin_amdgcn_s_barrier();

  int cur = 0;
  for (int t = 0; t < nt; ++t) {
    const unsigned short* la = &lA[cur][0];
    const unsigned short* lb = &lB[cur][0];
    const bool deep = (t + 2 < nt);

    s16x8 af[4], bfv[2];
#pragma unroll
    for (int m = 0; m < 4; ++m) af[m] = *(const s16x8*)&la[aoff + m * 1024 + kc0];
#pragma unroll
    for (int n = 0; n < 2; ++n) bfv[n] = *(const s16x8*)&lb[boff + n * 1024 + kc0];
    if (deep) { int nbuf = (cur + 2 == 3) ? 0 : ((cur + 2 == 4) ? 1 : cur + 2); STG2(nbuf, (t + 2) << 6); }
    __builtin_amdgcn_s_barrier();
    asm volatile("s_waitcnt lgkmcnt(0)" ::: "memory");
    __builtin_amdgcn_sched_barrier(0);
    __builtin_amdgcn_s_setprio(1);
#pragma unroll
    for (int m = 0; m < 4; ++m)
#pragma unroll
      for (int n = 0; n < 2; ++n)
        acc[m][n] = mfma16(af[m], bfv[n], acc[m][n]);
    __builtin_amdgcn_s_setprio(0);
    __builtin_amdgcn_s_barrier();

#pragma unroll
    for (int m = 0; m < 4; ++m) af[m] = *(const s16x8*)&la[aoff + m * 1024 + kc1];
#pragma unroll
    for (int n = 0; n < 2; ++n) bfv[n] = *(const s16x8*)&lb[boff + n * 1024 + kc1];
    __builtin_amdgcn_s_barrier();
    asm volatile("s_waitcnt lgkmcnt(0)" ::: "memory");
    __builtin_amdgcn_sched_barrier(0);
    __builtin_amdgcn_s_setprio(1);
#pragma unroll
    for (int m = 0; m < 4; ++m)
#pragma unroll
      for (int n = 0; n < 2; ++n)
        acc[m][n] = mfma16(af[m], bfv[n], acc[m][n]);
    __builtin_amdgcn_s_setprio(0);
    if (t + 1 < nt) {
      if (deep) asm volatile("s_waitcnt vmcnt(6)" ::: "memory");
      else      asm volatile("s_waitcnt vmcnt(0)" ::: "memory");
      __builtin_amdgcn_s_barrier();
    }
    cur = (cur == 2) ? 0 : cur + 1;
  }
#undef STG2

#pragma unroll
  for (int m = 0; m < 4; ++m)
#pragma unroll
    for (int n = 0; n < 2; ++n)
#pragma unroll
      for (int j = 0; j < 4; ++j) {
        int r = row0 + wr * 64 + m * 16 + lg * 4 + j;
        int c = col0 + wc * 32 + n * 16 + l15;
        if (obf) ((unsigned short*)Cout)[(size_t)r * Nn + c] = f2bf(acc[m][n][j]);
        else     ((float*)Cout)[(size_t)r * Nn + c] = acc[m][n][j];
      }
}

// ---- kernel 4: attention (round-18 version: h<->15-h quad pairing, THR=40)
__global__ __launch_bounds__(256, 4) void attn_kernel(const unsigned short* __restrict__ qkv,
                                                      const unsigned short* __restrict__ vt,
                                                      unsigned short* __restrict__ ctx) {
  __shared__ __align__(16) unsigned char smem[32768];
  unsigned short* kl0 = (unsigned short*)smem;             // [2][64*64] u16, 16KB
  unsigned short* vl0 = (unsigned short*)(smem + 16384);   // [2][64*64] u16, 16KB
  float* red = (float*)smem;

  const int bid = blockIdx.x;
  const int p_ = bid >> 8;          // 0..3 (slot within quad)
  const int s_ = (bid >> 5) & 7;    // 0..7
  const int g_ = bid & 31;          // (batch, head-group)
  const int hh = g_ & 15, bb_ = g_ >> 4;
  int h_, x32;
  if (p_ == 0)      { h_ = hh;      x32 = s_;      }
  else if (p_ == 1) { h_ = hh;      x32 = 31 - s_; }
  else if (p_ == 2) { h_ = 15 - hh; x32 = 15 - s_; }
  else              { h_ = 15 - hh; x32 = 16 + s_; }
  const int bh = bb_ * 16 + h_;
  const int b = bb_, h = h_;

  const int tid = threadIdx.x;
  const int wid = tid >> 6, lane = tid & 63;
  const int wr = wid & 1, wk = wid >> 1;
  const int l31 = lane & 31, hi = lane >> 5;
  const int i_base = x32 * 64 + wr * 32;

  const unsigned short* qb  = qkv + (size_t)b * TT * TN3 + h * THD;
  const unsigned short* kb_ = qkv + (size_t)b * TT * TN3 + TD + h * THD;
  const unsigned short* vb_ = vt + (size_t)bh * THD * TT;

  const float LOG2E = 1.44269504f;
  const float SL2 = exp2f(-0.5f * (float)(h + 1)) * LOG2E;
  const float SC2 = 0.125f * LOG2E;
  const float dbias = -SL2 * 64.0f;

  const int t_rel = (int)((40.0f / SL2 + 63.0f) * (1.0f / 64.0f)) + 1;
  const int t_end = (32 < x32 + t_rel) ? 32 : x32 + t_rel;

  const int srow = tid >> 3;
  const int sx = ((tid & 7) ^ (srow & 7)) * 8;
  const unsigned short* srcK = kb_ + (size_t)(x32 * 64 + srow) * TN3 + sx;
  const unsigned short* srcV = vb_ + (size_t)srow * TT + x32 * 64 + sx;
  const size_t kstep = (size_t)64 * TN3;

#define STAGE(bufi) do {                                   \
    unsigned short* _dk = kl0 + (bufi) * 4096 + tid * 8;   \
    unsigned short* _dv = vl0 + (bufi) * 4096 + tid * 8;   \
    gload_lds16(srcK,            _dk);                     \
    gload_lds16(srcK + 32 * TN3, _dk + 2048);              \
    gload_lds16(srcV,            _dv);                     \
    gload_lds16(srcV + 32 * TT,  _dv + 2048);              \
  } while (0)

  s16x8 qa[4];
  {
    const unsigned short* qr = qb + (size_t)(i_base + l31) * TN3 + hi * 8;
#pragma unroll
    for (int dd = 0; dd < 4; ++dd) qa[dd] = *(const s16x8*)(qr + dd * 16);
  }

  s16x8 ones;
  {
    short ov = (l31 == 0) ? (short)0x3F80 : (short)0;
#pragma unroll
    for (int e = 0; e < 8; ++e) ones[e] = ov;
  }

  float base[16];
#pragma unroll
  for (int r = 0; r < 16; ++r) {
    int cr0 = (r & 3) + 8 * (r >> 2);
    base[r] = -SL2 * (float)(wk * 32 + cr0 + 4 * hi - wr * 32 - l31) - 16.0f;
  }

  f32x16 o0, o1, ol;
#pragma unroll
  for (int r = 0; r < 16; ++r) { o0[r] = 0.f; o1[r] = 0.f; ol[r] = 0.f; }

  const int sw = (l31 & 7) << 4;
  int cc[4];
#pragma unroll
  for (int dd = 0; dd < 4; ++dd) cc[dd] = ((dd * 32 + hi * 16) ^ sw) >> 1;

  int cur = 0;
  STAGE(0); srcK += kstep; srcV += 64;
  asm volatile("s_waitcnt vmcnt(0)" ::: "memory");
  __syncthreads();

  for (int t = x32; t < t_end; ++t) {
    if (t + 1 < t_end) { STAGE(cur ^ 1); srcK += kstep; srcV += 64; }

    const unsigned short* kb = kl0 + cur * 4096;
    const unsigned short* vbl = vl0 + cur * 4096;

    f32x16 sv;
#pragma unroll
    for (int r = 0; r < 16; ++r) sv[r] = 0.f;
    __builtin_amdgcn_s_setprio(1);
#pragma unroll
    for (int dd = 0; dd < 4; ++dd) {
      s16x8 k0 = *(const s16x8*)&kb[(wk * 32 + l31) * 64 + cc[dd]];
      sv = mfma32(k0, qa[dd], sv);
    }
    __builtin_amdgcn_s_setprio(0);

    if (t == x32) {
#pragma unroll
      for (int r = 0; r < 16; ++r) {
        float bb = base[r];
        float v = __builtin_amdgcn_exp2f(fmaf(sv[r], SC2, bb));
        sv[r] = (bb > -15.999f) ? 0.0f : v;
      }
    } else {
#pragma unroll
      for (int r = 0; r < 16; ++r)
        sv[r] = __builtin_amdgcn_exp2f(fmaf(sv[r], SC2, base[r]));
    }
#pragma unroll
    for (int r = 0; r < 16; ++r) base[r] += dbias;

    s16x8 pa[2];
#pragma unroll
    for (int mh = 0; mh < 2; ++mh) {
      unsigned int a0 = cvtpk(sv[8 * mh + 0], sv[8 * mh + 1]);
      unsigned int a1 = cvtpk(sv[8 * mh + 2], sv[8 * mh + 3]);
      unsigned int b0 = cvtpk(sv[8 * mh + 4], sv[8 * mh + 5]);
      unsigned int b1 = cvtpk(sv[8 * mh + 6], sv[8 * mh + 7]);
      plswap(a0, b0); plswap(a1, b1);
      uint4 u; u.x = a0; u.y = a1; u.z = b0; u.w = b1;
      pa[mh] = __builtin_bit_cast(s16x8, u);
    }

    __builtin_amdgcn_s_setprio(1);
#pragma unroll
    for (int ks = 0; ks < 2; ++ks) {
      s16x8 v0 = *(const s16x8*)&vbl[l31 * 64 + cc[wk * 2 + ks]];
      s16x8 v1 = *(const s16x8*)&vbl[(32 + l31) * 64 + cc[wk * 2 + ks]];
      o0 = mfma32(pa[ks], v0, o0);
      o1 = mfma32(pa[ks], v1, o1);
      ol = mfma32(pa[ks], ones, ol);
    }
    __builtin_amdgcn_s_setprio(0);

    asm volatile("s_waitcnt vmcnt(0)" ::: "memory");
    __syncthreads();
    cur ^= 1;
  }
#undef STAGE

  const int rbase = (wr * 64 + lane) * 49;
  if (wk == 1) {
#pragma unroll
    for (int r = 0; r < 16; ++r) red[rbase + r] = o0[r];
#pragma unroll
    for (int r = 0; r < 16; ++r) red[rbase + 16 + r] = o1[r];
#pragma unroll
    for (int r = 0; r < 16; ++r) red[rbase + 32 + r] = ol[r];
  }
  __syncthreads();
  if (wk == 0) {
#pragma unroll
    for (int r = 0; r < 16; ++r) o0[r] += red[rbase + r];
#pragma unroll
    for (int r = 0; r < 16; ++r) o1[r] += red[rbase + 16 + r];
#pragma unroll
    for (int r = 0; r < 16; ++r) ol[r] += red[rbase + 32 + r];

    float rdiv[16];
#pragma unroll
    for (int r = 0; r < 16; ++r) rdiv[r] = 1.0f / __shfl(ol[r], lane & 32);

    unsigned short* cb = ctx + (size_t)(b * TT + i_base) * TD + h * THD + l31;
#pragma unroll
    for (int r = 0; r < 16; ++r) {
      int row = (r & 3) + 8 * (r >> 2) + 4 * hi;
      unsigned int pk = cvtpk(o0[r] * rdiv[r], o1[r] * rdiv[r]);
      cb[(size_t)row * TD] = (unsigned short)pk;
      cb[(size_t)row * TD + 32] = (unsigned short)(pk >> 16);
    }
  }
}

extern "C" void kernel_launch(void* const* d_in, const int* in_sizes, int n_in,
                              void* d_out, int out_size, void* d_ws, size_t ws_size,
                              hipStream_t stream) {
  const void* x    = d_in[0];
  const void* wqkv = d_in[1];
  const void* wout = d_in[2];
  char* ws = (char*)d_ws;
  unsigned short* xb    = (unsigned short*)(ws + WS_XB);
  unsigned short* wqkvt = (unsigned short*)(ws + WS_WQKVT);
  unsigned short* woutt = (unsigned short*)(ws + WS_WOUTT);
  unsigned short* qkvb  = (unsigned short*)(ws + WS_QKV);
  unsigned short* vtb   = (unsigned short*)(ws + WS_VT);
  unsigned short* ctxb  = (unsigned short*)(ws + WS_CTX);

  prep_kernel<<<3072, 256, 0, stream>>>(x, wqkv, wout, xb, wqkvt, woutt);
  gemm1_kernel<<<(TM / 256) * (TN3 / 192), 512, 0, stream>>>(xb, (const unsigned short*)x, wqkvt, qkvb, vtb, TM, TN3, TD);
  attn_kernel<<<1024, 256, 0, stream>>>(qkvb, vtb, ctxb);
  gemm_bt2_kernel<<<dim3(TM / 128, TD / 64), 256, 0, stream>>>(ctxb, woutt, d_out, TM, TD, TD, (const unsigned short*)x);
}

// Round 20
// 94.442 us; speedup vs baseline: 1.0138x; 1.0138x over previous
//
#include <hip/hip_runtime.h>

#define DEV __device__ __forceinline__

typedef __attribute__((ext_vector_type(4))) float f32x4;
typedef __attribute__((ext_vector_type(16))) float f32x16;
typedef __attribute__((ext_vector_type(8))) short s16x8;

static constexpr int TB  = 2;
static constexpr int TT  = 2048;
static constexpr int TD  = 1024;
static constexpr int TH  = 16;
static constexpr int THD = 64;
static constexpr int TN3 = 3072;
static constexpr int TM  = TB * TT;   // 4096

// ---- workspace layout (bytes) ----
#define WS_XB     1024u                       // bf16 [4096][1024]      8 MiB
#define WS_WQKVT  (WS_XB + 8388608u)          // bf16 [3072][1024]      6 MiB
#define WS_WOUTT  (WS_WQKVT + 6291456u)       // bf16 [1024][1024]      2 MiB
#define WS_QKV    (WS_WOUTT + 2097152u)       // bf16 [4096][3072]     24 MiB
#define WS_VT     (WS_QKV + 25165824u)        // bf16 [32][64][2048]    8 MiB
#define WS_CTX    (WS_VT + 8388608u)          // bf16 [4096][1024]      8 MiB

DEV unsigned short f2bf(float f) {
  unsigned int u = __builtin_bit_cast(unsigned int, f);
  u += 0x7FFFu + ((u >> 16) & 1u);
  return (unsigned short)(u >> 16);
}
DEV f32x4 mfma16(s16x8 a, s16x8 b, f32x4 c) {
  return __builtin_amdgcn_mfma_f32_16x16x32_bf16(a, b, c, 0, 0, 0);
}
DEV f32x16 mfma32(s16x8 a, s16x8 b, f32x16 c) {
  return __builtin_amdgcn_mfma_f32_32x32x16_bf16(a, b, c, 0, 0, 0);
}
DEV void gload_lds16(const void* g, void* l) {
  __builtin_amdgcn_global_load_lds(
      (const __attribute__((address_space(1))) void*)g,
      (__attribute__((address_space(3))) void*)l, 16, 0, 0);
}
DEV unsigned int cvtpk(float lo, float hi_) {
  unsigned int r;
  asm("v_cvt_pk_bf16_f32 %0, %1, %2" : "=v"(r) : "v"(lo), "v"(hi_));
  return r;
}
DEV void plswap(unsigned int& a, unsigned int& b) {
  asm("v_permlane32_swap_b32 %0, %1" : "+v"(a), "+v"(b));
}

// ---- inline dtype probe: wave-uniform. fp32 viewed as u16 -> ~47% of even
// samples have exp>=135; bf16 N(0,1) -> exactly 0.
DEV bool is_bf16(const void* x) {
  uint4 v = ((const uint4*)x)[threadIdx.x & 63];
  unsigned int w[4] = {v.x, v.y, v.z, v.w};
  int hit = 0;
#pragma unroll
  for (int k = 0; k < 4; ++k) {
    if (((w[k] >> 7) & 0xFF) >= 135) hit++;
    if (((w[k] >> 23) & 0xFF) >= 135) hit++;
  }
  return __ballot(hit > 0) == 0ULL;
}

// ---- kernel 1: fused prep: W transposes (blocks 0..1023) + x cast (1024..3071;
// cast skipped when input already bf16 since GEMM1 then reads x directly)
__global__ __launch_bounds__(256) void prep_kernel(const void* __restrict__ x,
                                                   const void* __restrict__ wqkv,
                                                   const void* __restrict__ wout,
                                                   unsigned short* __restrict__ xb,
                                                   unsigned short* __restrict__ wqkvt,
                                                   unsigned short* __restrict__ woutt) {
  __shared__ unsigned short tile[64 * 65];
  const int bid = blockIdx.x;
  const bool bf = is_bf16(x);
  if (bid < 1024) {
    const void* W; unsigned short* Wt; int N, k0, n0;
    if (bid < 768) { W = wqkv; Wt = wqkvt; N = TN3; k0 = (bid & 15) * 64; n0 = (bid >> 4) * 64; }
    else { int id = bid - 768; W = wout; Wt = woutt; N = TD; k0 = (id & 15) * 64; n0 = (id >> 4) * 64; }
    for (int e = threadIdx.x; e < 4096; e += 256) {
      int kr = e >> 6, nc = e & 63;
      unsigned short v;
      if (bf) v = ((const unsigned short*)W)[(size_t)(k0 + kr) * N + n0 + nc];
      else    v = f2bf(((const float*)W)[(size_t)(k0 + kr) * N + n0 + nc]);
      tile[kr * 65 + nc] = v;
    }
    __syncthreads();
    for (int e = threadIdx.x; e < 4096; e += 256) {
      int nr = e >> 6, kc = e & 63;
      Wt[(size_t)(n0 + nr) * TD + k0 + kc] = tile[kc * 65 + nr];
    }
  } else {
    if (bf) return;   // GEMM1 reads x directly in bf16 mode
    int i = (bid - 1024) * 256 + threadIdx.x;
    if (i >= (TM * TD) / 8) return;
    const float* s = (const float*)x + (size_t)i * 8;
    unsigned int w0 = (unsigned int)f2bf(s[0]) | ((unsigned int)f2bf(s[1]) << 16);
    unsigned int w1 = (unsigned int)f2bf(s[2]) | ((unsigned int)f2bf(s[3]) << 16);
    unsigned int w2 = (unsigned int)f2bf(s[4]) | ((unsigned int)f2bf(s[5]) << 16);
    unsigned int w3 = (unsigned int)f2bf(s[6]) | ((unsigned int)f2bf(s[7]) << 16);
    uint4 o; o.x = w0; o.y = w1; o.z = w2; o.w = w3;
    ((uint4*)xb)[i] = o;
  }
}

// ---- kernel 2: 256x192-tile GEMM1 (round-10/16 best-measured config).
// 256 blocks = full CU fill, BK=64, 8 waves (2M x 4N, per-wave 128x48),
// 2 phases/K-tile: {read k-half | stage half of t+1 | barrier | lgkmcnt(0) |
// 24 MFMA} x2, one vmcnt(0)/tile on >=1-phase-old loads, XOR swizzle, 112KB.
// Fused V-transpose epilogue for output columns >= 2048.
__global__ __launch_bounds__(512, 2) void gemm1_kernel(const unsigned short* __restrict__ Axb,
                                                       const unsigned short* __restrict__ xraw,
                                                       const unsigned short* __restrict__ Bt,
                                                       unsigned short* __restrict__ C,
                                                       unsigned short* __restrict__ vtb,
                                                       int Mn, int Nn, int Kn) {
  __shared__ unsigned short lA[2][256 * 64];   // 32KB each
  __shared__ unsigned short lB[2][192 * 64];   // 24KB each
  const int tid = threadIdx.x;
  const int lane = tid & 63;
  const int wid = tid >> 6;                 // 0..7
  const int wm = wid >> 2, wn = wid & 3;    // 2M x 4N
  const int l15 = lane & 15, lg = lane >> 4;

  const int nby = Nn / 192;                 // 16
  const int nwg = (Mn >> 8) * nby;          // 256
  const int cpx = nwg >> 3;
  const int bid = blockIdx.x;
  const int swz = (bid & 7) * cpx + (bid >> 3);
  const int bm = swz / nby, bn = swz % nby;
  const int row0 = bm << 8, col0 = bn * 192;

  const bool bf = is_bf16(xraw);
  const unsigned short* Abase = bf ? xraw : Axb;

  const int srow = tid >> 3;                // 0..63
  const int scol = ((tid & 7) ^ (srow & 7)) * 8;
  const unsigned short* aS = Abase + (size_t)(row0 + srow) * Kn + scol;
  const unsigned short* bS = Bt + (size_t)(col0 + srow) * Kn + scol;
  const size_t r64 = (size_t)64 * Kn;

#define STGA(dst, koff) do {                                \
    unsigned short* _d = (dst) + tid * 8;                   \
    const unsigned short* _s = aS + (koff);                 \
    gload_lds16(_s,           _d);                          \
    gload_lds16(_s + r64,     _d + 4096);                   \
    gload_lds16(_s + 2 * r64, _d + 8192);                   \
    gload_lds16(_s + 3 * r64, _d + 12288);                  \
  } while (0)
#define STGB(dst, koff) do {                                \
    unsigned short* _d = (dst) + tid * 8;                   \
    const unsigned short* _s = bS + (koff);                 \
    gload_lds16(_s,           _d);                          \
    gload_lds16(_s + r64,     _d + 4096);                   \
    gload_lds16(_s + 2 * r64, _d + 8192);                   \
  } while (0)

  f32x4 acc[8][3];
#pragma unroll
  for (int m = 0; m < 8; ++m)
#pragma unroll
    for (int n = 0; n < 3; ++n) acc[m][n] = (f32x4){0.f, 0.f, 0.f, 0.f};

  const int sa = l15 & 7;
  const int kc0 = (lg ^ sa) * 8;
  const int kc1 = ((4 + lg) ^ sa) * 8;
  const int aRow = (wm * 128 + l15) * 64;
  const int bRow = (wn * 48 + l15) * 64;

  STGA(&lA[0][0], 0);
  STGB(&lB[0][0], 0);
  asm volatile("s_waitcnt vmcnt(0)" ::: "memory");
  __builtin_amdgcn_s_barrier();

  const int nt = Kn >> 6;
  for (int t = 0; t < nt; ++t) {
    const unsigned short* la = &lA[t & 1][0];
    const unsigned short* lb = &lB[t & 1][0];
    unsigned short* na = &lA[(t + 1) & 1][0];
    unsigned short* nb = &lB[(t + 1) & 1][0];
    const int koff = (t + 1) << 6;
    const bool more = (t + 1 < nt);

    s16x8 af[8], bv[3];

    // ---- P1: read k0 (8 A + 3 B) | stage A(t+1) | barrier | 24 MFMA
#pragma unroll
    for (int m = 0; m < 8; ++m) af[m] = *(const s16x8*)&la[aRow + m * 1024 + kc0];
#pragma unroll
    for (int n = 0; n < 3; ++n) bv[n] = *(const s16x8*)&lb[bRow + n * 1024 + kc0];
    if (more) STGA(na, koff);
    __builtin_amdgcn_s_barrier();
    asm volatile("s_waitcnt lgkmcnt(0)" ::: "memory");
    __builtin_amdgcn_sched_barrier(0);
    __builtin_amdgcn_s_setprio(1);
#pragma unroll
    for (int m = 0; m < 8; ++m)
#pragma unroll
      for (int n = 0; n < 3; ++n)
        acc[m][n] = mfma16(af[m], bv[n], acc[m][n]);
    __builtin_amdgcn_s_setprio(0);
    __builtin_amdgcn_s_barrier();

    // ---- P2: read k1 | stage B(t+1) | barrier | 24 MFMA | vmcnt(0) | barrier
#pragma unroll
    for (int m = 0; m < 8; ++m) af[m] = *(const s16x8*)&la[aRow + m * 1024 + kc1];
#pragma unroll
    for (int n = 0; n < 3; ++n) bv[n] = *(const s16x8*)&lb[bRow + n * 1024 + kc1];
    if (more) STGB(nb, koff);
    __builtin_amdgcn_s_barrier();
    asm volatile("s_waitcnt lgkmcnt(0)" ::: "memory");
    __builtin_amdgcn_sched_barrier(0);
    __builtin_amdgcn_s_setprio(1);
#pragma unroll
    for (int m = 0; m < 8; ++m)
#pragma unroll
      for (int n = 0; n < 3; ++n)
        acc[m][n] = mfma16(af[m], bv[n], acc[m][n]);
    __builtin_amdgcn_s_setprio(0);
    asm volatile("s_waitcnt vmcnt(0)" ::: "memory");
    __builtin_amdgcn_s_barrier();
  }
#undef STGA
#undef STGB

  // epilogue: per-fragment branch at column 2048 (fragments never straddle)
  unsigned short* cw = C + (size_t)(row0 + wm * 128 + lg * 4) * Nn + col0 + wn * 48 + l15;
#pragma unroll
  for (int m = 0; m < 8; ++m)
#pragma unroll
    for (int n = 0; n < 3; ++n) {
      const int cbase = col0 + wn * 48 + n * 16;
      if (cbase < 2048) {
#pragma unroll
        for (int j = 0; j < 4; ++j)
          cw[(size_t)(m * 16 + j) * Nn + n * 16] = f2bf(acc[m][n][j]);
      } else {
        int tg = row0 + wm * 128 + lg * 4 + m * 16;
        int bb = tg >> 11, tt = tg & 2047;
        int cc2 = cbase + l15 - 2048;
        int h = cc2 >> 6, d = cc2 & 63;
        unsigned short* dst = vtb + (((size_t)(bb * 16 + h) * 64 + d) << 11) + tt;
        uint2 pk;
        pk.x = cvtpk(acc[m][n][0], acc[m][n][1]);
        pk.y = cvtpk(acc[m][n][2], acc[m][n][3]);
        *(uint2*)dst = pk;
      }
    }
}

// ---- kernel 3: GEMM2 (round-13..16 validated version)
__global__ __launch_bounds__(256, 2) void gemm_bt2_kernel(const unsigned short* __restrict__ A,
                                                          const unsigned short* __restrict__ Bt,
                                                          void* __restrict__ Cout,
                                                          int Mn, int Nn, int Kn,
                                                          const unsigned short* __restrict__ xprobe) {
  __shared__ unsigned short lA[3][128 * 64];   // 16KB each
  __shared__ unsigned short lB[3][64 * 64];    // 8KB each
  const int tid  = threadIdx.x;
  const int lane = tid & 63, wid = tid >> 6;
  const int wr = wid >> 1, wc = wid & 1;       // 2M x 2N waves
  const int l15 = lane & 15, lg = lane >> 4;
  const int row0 = blockIdx.x * 128, col0 = blockIdx.y * 64;

  const bool obf = is_bf16(xprobe);

  f32x4 acc[4][2];
#pragma unroll
  for (int m = 0; m < 4; ++m)
#pragma unroll
    for (int n = 0; n < 2; ++n) acc[m][n] = (f32x4){0.f, 0.f, 0.f, 0.f};

  const int srow = tid >> 3;
  const int scol = ((tid & 7) ^ (srow & 7)) * 8;
  const unsigned short* aS = A  + (size_t)(row0 + srow) * Kn + scol;
  const unsigned short* bS = Bt + (size_t)(col0 + srow) * Kn + scol;
  const size_t r32 = (size_t)32 * Kn;

#define STG2(bi, koff) do {                                                 \
    unsigned short* _da = &lA[bi][0] + tid * 8;                             \
    unsigned short* _db = &lB[bi][0] + tid * 8;                             \
    gload_lds16(aS + (koff),            _da);                               \
    gload_lds16(aS + (koff) + r32,      _da + 2048);                        \
    gload_lds16(aS + (koff) + 2 * r32,  _da + 4096);                        \
    gload_lds16(aS + (koff) + 3 * r32,  _da + 6144);                        \
    gload_lds16(bS + (koff),            _db);                               \
    gload_lds16(bS + (koff) + r32,      _db + 2048);                        \
  } while (0)

  const int sa = l15 & 7;
  const int kc0 = (lg ^ sa) * 8;
  const int kc1 = ((4 + lg) ^ sa) * 8;
  const int aoff = (wr * 64 + l15) * 64;   // + m*1024
  const int boff = (wc * 32 + l15) * 64;   // + n*1024

  const int nt = Kn >> 6;
  STG2(0, 0);
  STG2(1, 64);
  asm volatile("s_waitcnt vmcnt(6)" ::: "memory");
  __builtin_amdgcn_s_barrier();

  int cur = 0;
  for (int t = 0; t < nt; ++t) {
    const unsigned short* la = &lA[cur][0];
    const unsigned short* lb = &lB[cur][0];
    const bool deep = (t + 2 < nt);

    s16x8 af[4], bfv[2];
#pragma unroll
    for (int m = 0; m < 4; ++m) af[m] = *(const s16x8*)&la[aoff + m * 1024 + kc0];
#pragma unroll
    for (int n = 0; n < 2; ++n) bfv[n] = *(const s16x8*)&lb[boff + n * 1024 + kc0];
    if (deep) { int nbuf = (cur + 2 == 3) ? 0 : ((cur + 2 == 4) ? 1 : cur + 2); STG2(nbuf, (t + 2) << 6); }
    __builtin_amdgcn_s_barrier();
    asm volatile("s_waitcnt lgkmcnt(0)" ::: "memory");
    __builtin_amdgcn_sched_barrier(0);
    __builtin_amdgcn_s_setprio(1);
#pragma unroll
    for (int m = 0; m < 4; ++m)
#pragma unroll
      for (int n = 0; n < 2; ++n)
        acc[m][n] = mfma16(af[m], bfv[n], acc[m][n]);
    __builtin_amdgcn_s_setprio(0);
    __builtin_amdgcn_s_barrier();

#pragma unroll
    for (int m = 0; m < 4; ++m) af[m] = *(const s16x8*)&la[aoff + m * 1024 + kc1];
#pragma unroll
    for (int n = 0; n < 2; ++n) bfv[n] = *(const s16x8*)&lb[boff + n * 1024 + kc1];
    __builtin_amdgcn_s_barrier();
    asm volatile("s_waitcnt lgkmcnt(0)" ::: "memory");
    __builtin_amdgcn_sched_barrier(0);
    __builtin_amdgcn_s_setprio(1);
#pragma unroll
    for (int m = 0; m < 4; ++m)
#pragma unroll
      for (int n = 0; n < 2; ++n)
        acc[m][n] = mfma16(af[m], bfv[n], acc[m][n]);
    __builtin_amdgcn_s_setprio(0);
    if (t + 1 < nt) {
      if (deep) asm volatile("s_waitcnt vmcnt(6)" ::: "memory");
      else      asm volatile("s_waitcnt vmcnt(0)" ::: "memory");
      __builtin_amdgcn_s_barrier();
    }
    cur = (cur == 2) ? 0 : cur + 1;
  }
#undef STG2

#pragma unroll
  for (int m = 0; m < 4; ++m)
#pragma unroll
    for (int n = 0; n < 2; ++n)
#pragma unroll
      for (int j = 0; j < 4; ++j) {
        int r = row0 + wr * 64 + m * 16 + lg * 4 + j;
        int c = col0 + wc * 32 + n * 16 + l15;
        if (obf) ((unsigned short*)Cout)[(size_t)r * Nn + c] = f2bf(acc[m][n][j]);
        else     ((float*)Cout)[(size_t)r * Nn + c] = acc[m][n][j];
      }
}

// ---- kernel 4: attention, static mapping with complement-paired quads:
// quad = {(g,s), (g^16, 31-s), (g+8, 15-s), ((g+8)^16, 16+s)} -> heavy head's
// x and 31-x land in the same quad (sum == 33 for T=32). THR=40 truncation.
__global__ __launch_bounds__(256, 4) void attn_kernel(const unsigned short* __restrict__ qkv,
                                                      const unsigned short* __restrict__ vt,
                                                      unsigned short* __restrict__ ctx) {
  __shared__ __align__(16) unsigned char smem[32768];
  unsigned short* kl0 = (unsigned short*)smem;             // [2][64*64] u16, 16KB
  unsigned short* vl0 = (unsigned short*)(smem + 16384);   // [2][64*64] u16, 16KB
  float* red = (float*)smem;

  const int bid = blockIdx.x;
  const int q_ = bid >> 8;          // 0..3
  const int s_ = (bid >> 5) & 7;    // 0..7
  const int g_ = bid & 31;          // 0..31
  int bh, x32;
  if (q_ == 0)      { bh = g_;                   x32 = s_;      }
  else if (q_ == 1) { bh = g_ ^ 16;              x32 = 31 - s_; }
  else if (q_ == 2) { bh = (g_ + 8) & 31;        x32 = 15 - s_; }
  else              { bh = ((g_ + 8) & 31) ^ 16; x32 = 16 + s_; }
  const int b = bh >> 4, h = bh & 15;

  const int tid = threadIdx.x;
  const int wid = tid >> 6, lane = tid & 63;
  const int wr = wid & 1, wk = wid >> 1;
  const int l31 = lane & 31, hi = lane >> 5;
  const int i_base = x32 * 64 + wr * 32;

  const unsigned short* qb  = qkv + (size_t)b * TT * TN3 + h * THD;
  const unsigned short* kb_ = qkv + (size_t)b * TT * TN3 + TD + h * THD;
  const unsigned short* vb_ = vt + (size_t)bh * THD * TT;

  const float LOG2E = 1.44269504f;
  const float SL2 = exp2f(-0.5f * (float)(h + 1)) * LOG2E;
  const float SC2 = 0.125f * LOG2E;
  const float dbias = -SL2 * 64.0f;

  const int t_rel = (int)((40.0f / SL2 + 63.0f) * (1.0f / 64.0f)) + 1;
  const int t_end = (32 < x32 + t_rel) ? 32 : x32 + t_rel;

  const int srow = tid >> 3;
  const int sx = ((tid & 7) ^ (srow & 7)) * 8;
  const unsigned short* srcK = kb_ + (size_t)(x32 * 64 + srow) * TN3 + sx;
  const unsigned short* srcV = vb_ + (size_t)srow * TT + x32 * 64 + sx;
  const size_t kstep = (size_t)64 * TN3;

#define STAGE(bufi) do {                                   \
    unsigned short* _dk = kl0 + (bufi) * 4096 + tid * 8;   \
    unsigned short* _dv = vl0 + (bufi) * 4096 + tid * 8;   \
    gload_lds16(srcK,            _dk);                     \
    gload_lds16(srcK + 32 * TN3, _dk + 2048);              \
    gload_lds16(srcV,            _dv);                     \
    gload_lds16(srcV + 32 * TT,  _dv + 2048);              \
  } while (0)

  s16x8 qa[4];
  {
    const unsigned short* qr = qb + (size_t)(i_base + l31) * TN3 + hi * 8;
#pragma unroll
    for (int dd = 0; dd < 4; ++dd) qa[dd] = *(const s16x8*)(qr + dd * 16);
  }

  s16x8 ones;
  {
    short ov = (l31 == 0) ? (short)0x3F80 : (short)0;
#pragma unroll
    for (int e = 0; e < 8; ++e) ones[e] = ov;
  }

  float base[16];
#pragma unroll
  for (int r = 0; r < 16; ++r) {
    int cr0 = (r & 3) + 8 * (r >> 2);
    base[r] = -SL2 * (float)(wk * 32 + cr0 + 4 * hi - wr * 32 - l31) - 16.0f;
  }

  f32x16 o0, o1, ol;
#pragma unroll
  for (int r = 0; r < 16; ++r) { o0[r] = 0.f; o1[r] = 0.f; ol[r] = 0.f; }

  const int sw = (l31 & 7) << 4;
  int cc[4];
#pragma unroll
  for (int dd = 0; dd < 4; ++dd) cc[dd] = ((dd * 32 + hi * 16) ^ sw) >> 1;

  int cur = 0;
  STAGE(0); srcK += kstep; srcV += 64;
  asm volatile("s_waitcnt vmcnt(0)" ::: "memory");
  __syncthreads();

  for (int t = x32; t < t_end; ++t) {
    if (t + 1 < t_end) { STAGE(cur ^ 1); srcK += kstep; srcV += 64; }

    const unsigned short* kb = kl0 + cur * 4096;
    const unsigned short* vbl = vl0 + cur * 4096;

    f32x16 sv;
#pragma unroll
    for (int r = 0; r < 16; ++r) sv[r] = 0.f;
    __builtin_amdgcn_s_setprio(1);
#pragma unroll
    for (int dd = 0; dd < 4; ++dd) {
      s16x8 k0 = *(const s16x8*)&kb[(wk * 32 + l31) * 64 + cc[dd]];
      sv = mfma32(k0, qa[dd], sv);
    }
    __builtin_amdgcn_s_setprio(0);

    if (t == x32) {
#pragma unroll
      for (int r = 0; r < 16; ++r) {
        float bb = base[r];
        float v = __builtin_amdgcn_exp2f(fmaf(sv[r], SC2, bb));
        sv[r] = (bb > -15.999f) ? 0.0f : v;
      }
    } else {
#pragma unroll
      for (int r = 0; r < 16; ++r)
        sv[r] = __builtin_amdgcn_exp2f(fmaf(sv[r], SC2, base[r]));
    }
#pragma unroll
    for (int r = 0; r < 16; ++r) base[r] += dbias;

    s16x8 pa[2];
#pragma unroll
    for (int mh = 0; mh < 2; ++mh) {
      unsigned int a0 = cvtpk(sv[8 * mh + 0], sv[8 * mh + 1]);
      unsigned int a1 = cvtpk(sv[8 * mh + 2], sv[8 * mh + 3]);
      unsigned int b0 = cvtpk(sv[8 * mh + 4], sv[8 * mh + 5]);
      unsigned int b1 = cvtpk(sv[8 * mh + 6], sv[8 * mh + 7]);
      plswap(a0, b0); plswap(a1, b1);
      uint4 u; u.x = a0; u.y = a1; u.z = b0; u.w = b1;
      pa[mh] = __builtin_bit_cast(s16x8, u);
    }

    __builtin_amdgcn_s_setprio(1);
#pragma unroll
    for (int ks = 0; ks < 2; ++ks) {
      s16x8 v0 = *(const s16x8*)&vbl[l31 * 64 + cc[wk * 2 + ks]];
      s16x8 v1 = *(const s16x8*)&vbl[(32 + l31) * 64 + cc[wk * 2 + ks]];
      o0 = mfma32(pa[ks], v0, o0);
      o1 = mfma32(pa[ks], v1, o1);
      ol = mfma32(pa[ks], ones, ol);
    }
    __builtin_amdgcn_s_setprio(0);

    asm volatile("s_waitcnt vmcnt(0)" ::: "memory");
    __syncthreads();
    cur ^= 1;
  }
#undef STAGE

  const int rbase = (wr * 64 + lane) * 49;
  if (wk == 1) {
#pragma unroll
    for (int r = 0; r < 16; ++r) red[rbase + r] = o0[r];
#pragma unroll
    for (int r = 0; r < 16; ++r) red[rbase + 16 + r] = o1[r];
#pragma unroll
    for (int r = 0; r < 16; ++r) red[rbase + 32 + r] = ol[r];
  }
  __syncthreads();
  if (wk == 0) {
#pragma unroll
    for (int r = 0; r < 16; ++r) o0[r] += red[rbase + r];
#pragma unroll
    for (int r = 0; r < 16; ++r) o1[r] += red[rbase + 16 + r];
#pragma unroll
    for (int r = 0; r < 16; ++r) ol[r] += red[rbase + 32 + r];

    float rdiv[16];
#pragma unroll
    for (int r = 0; r < 16; ++r) rdiv[r] = 1.0f / __shfl(ol[r], lane & 32);

    unsigned short* cb = ctx + (size_t)(b * TT + i_base) * TD + h * THD + l31;
#pragma unroll
    for (int r = 0; r < 16; ++r) {
      int row = (r & 3) + 8 * (r >> 2) + 4 * hi;
      unsigned int pk = cvtpk(o0[r] * rdiv[r], o1[r] * rdiv[r]);
      cb[(size_t)row * TD] = (unsigned short)pk;
      cb[(size_t)row * TD + 32] = (unsigned short)(pk >> 16);
    }
  }
}

extern "C" void kernel_launch(void* const* d_in, const int* in_sizes, int n_in,
                              void* d_out, int out_size, void* d_ws, size_t ws_size,
                              hipStream_t stream) {
  const void* x    = d_in[0];
  const void* wqkv = d_in[1];
  const void* wout = d_in[2];
  char* ws = (char*)d_ws;
  unsigned short* xb    = (unsigned short*)(ws + WS_XB);
  unsigned short* wqkvt = (unsigned short*)(ws + WS_WQKVT);
  unsigned short* woutt = (unsigned short*)(ws + WS_WOUTT);
  unsigned short* qkvb  = (unsigned short*)(ws + WS_QKV);
  unsigned short* vtb   = (unsigned short*)(ws + WS_VT);
  unsigned short* ctxb  = (unsigned short*)(ws + WS_CTX);

  prep_kernel<<<3072, 256, 0, stream>>>(x, wqkv, wout, xb, wqkvt, woutt);
  gemm1_kernel<<<(TM / 256) * (TN3 / 192), 512, 0, stream>>>(xb, (const unsigned short*)x, wqkvt, qkvb, vtb, TM, TN3, TD);
  attn_kernel<<<1024, 256, 0, stream>>>(qkvb, vtb, ctxb);
  gemm_bt2_kernel<<<dim3(TM / 128, TD / 64), 256, 0, stream>>>(ctxb, woutt, d_out, TM, TD, TD, (const unsigned short*)x);
}